// Round 9
// baseline (2496.373 us; speedup 1.0000x reference)
//
#include <hip/hip_runtime.h>
#include <hip/hip_bf16.h>
#include <math.h>

// ---------------- model constants ----------------
#define BATCH 64
#define CDIM 384
#define NHEADS 6
#define HD 64
#define MLPD 1536
#define NLAYERS 12
#define NPATCH 196
#define NTOK0 197
#define NCLS 100

typedef unsigned short ushortT;
typedef __attribute__((ext_vector_type(8))) short short8v;
typedef __attribute__((ext_vector_type(4))) float float4v;

// ---------------- bf16 helpers ----------------
__device__ inline ushortT f2b(float f) {
  union { float f; unsigned u; } x; x.f = f;
  unsigned r = x.u + 0x7fffu + ((x.u >> 16) & 1u);
  return (ushortT)(r >> 16);
}
__device__ inline float b2f(ushortT u) {
  union { unsigned u; float f; } x; x.u = ((unsigned)u) << 16;
  return x.f;
}

// async global->LDS, 16B per lane; lds base must be wave-uniform (HW: base + lane*16)
__device__ inline void gload_lds16(const ushortT* g, ushortT* l) {
  __builtin_amdgcn_global_load_lds((const __attribute__((address_space(1))) void*)g,
                                   (__attribute__((address_space(3))) void*)l, 16, 0, 0);
}

// ---------------- wave helpers ----------------
__device__ inline float wave_sum(float v) {
  #pragma unroll
  for (int o = 32; o > 0; o >>= 1) v += __shfl_xor(v, o);
  return v;
}

// ---------------- im2col: x[B,3,224,224] -> P[B*196, 768] bf16 ----------------
__global__ __launch_bounds__(256) void im2col_bf16(const float* __restrict__ x, ushortT* __restrict__ P) {
  int i = blockIdx.x * 256 + threadIdx.x;
  const int total = BATCH * NPATCH * 768;
  if (i >= total) return;
  int k = i % 768;
  int row = i / 768;
  int c = k >> 8;
  int r = k & 255;
  int py = r >> 4, px = r & 15;
  int b = row / NPATCH;
  int p = row % NPATCH;
  int gy = p / 14, gx = p % 14;
  P[i] = f2b(x[(((size_t)b * 3 + c) * 224 + gy * 16 + py) * 224 + gx * 16 + px]);
}

// ---------------- assemble ----------------
__global__ __launch_bounds__(256) void assemble_kernel(const float* __restrict__ patchout,
                                                       const float* __restrict__ cls_tok,
                                                       const float* __restrict__ pos,
                                                       float* __restrict__ h) {
  int i = blockIdx.x * 256 + threadIdx.x;
  const int total = BATCH * NTOK0 * CDIM;
  if (i >= total) return;
  int c = i % CDIM;
  int n = (i / CDIM) % NTOK0;
  int b = i / (CDIM * NTOK0);
  float v = (n == 0) ? cls_tok[c] : patchout[((size_t)b * NPATCH + (n - 1)) * CDIM + c];
  h[i] = v + pos[n * CDIM + c];
}

// ---------------- weight transpose + bf16 convert ----------------
__global__ __launch_bounds__(256) void wtrans_layer(const float* __restrict__ qkv_w, const float* __restrict__ proj_w,
                                                    const float* __restrict__ fc1_w, const float* __restrict__ fc2_w,
                                                    ushortT* __restrict__ wq, ushortT* __restrict__ wp,
                                                    ushortT* __restrict__ w1, ushortT* __restrict__ w2) {
  int id = blockIdx.x;
  const float* W; ushortT* O; int K, N, t;
  if (id < 432)       { W = qkv_w; O = wq; K = 384;  N = 1152; t = id; }
  else if (id < 576)  { W = proj_w; O = wp; K = 384; N = 384;  t = id - 432; }
  else if (id < 1152) { W = fc1_w; O = w1; K = 384;  N = 1536; t = id - 576; }
  else                { W = fc2_w; O = w2; K = 1536; N = 384;  t = id - 1152; }
  int tilesK = K >> 5;
  int k0 = (t % tilesK) << 5, n0 = (t / tilesK) << 5;
  __shared__ float tile[32][33];
  int tx = threadIdx.x & 31, ty = threadIdx.x >> 5;
  #pragma unroll
  for (int i = 0; i < 4; ++i)
    tile[ty + 8 * i][tx] = W[(size_t)(k0 + ty + 8 * i) * N + n0 + tx];
  __syncthreads();
  #pragma unroll
  for (int i = 0; i < 4; ++i)
    O[(size_t)(n0 + ty + 8 * i) * K + k0 + tx] = f2b(tile[tx][ty + 8 * i]);
}

// single matrix version (patch embed weights)
__global__ __launch_bounds__(256) void wtrans_one(const float* __restrict__ W, ushortT* __restrict__ O, int K, int N) {
  int t = blockIdx.x;
  int tilesK = K >> 5;
  int k0 = (t % tilesK) << 5, n0 = (t / tilesK) << 5;
  __shared__ float tile[32][33];
  int tx = threadIdx.x & 31, ty = threadIdx.x >> 5;
  #pragma unroll
  for (int i = 0; i < 4; ++i)
    tile[ty + 8 * i][tx] = W[(size_t)(k0 + ty + 8 * i) * N + n0 + tx];
  __syncthreads();
  #pragma unroll
  for (int i = 0; i < 4; ++i)
    O[(size_t)(n0 + ty + 8 * i) * K + k0 + tx] = f2b(tile[tx][ty + 8 * i]);
}

// ---------------- MFMA bf16 GEMM: 3-deep counted-vmcnt pipeline, XCD-swizzled ----------------
// out = act(A@Wt^T + bias) [+ res]; A:[M][K] bf16, Wt:[N][K] bf16. N%128==0, K%32==0, K>=96.
// Per iter: wait vmcnt(8) [tile t landed; t+1,t+2 in flight] -> barrier -> ds_read frags
// -> lgkmcnt(0)+sched_barrier -> barrier [all waves done reading buf] -> issue t+3 -> MFMA.
template<int ACT, int RES, int OBF>
__global__ __launch_bounds__(256) void gemm_mfma(const ushortT* __restrict__ A, const ushortT* __restrict__ Wt,
                                                 const float* __restrict__ bias, const float* __restrict__ res,
                                                 void* __restrict__ outp, int M, int N, int K, int gx) {
  __shared__ __align__(16) ushortT Asl[3][4096];  // [128][32] linear per buffer
  __shared__ __align__(16) ushortT Bsl[3][4096];
  const int tid = threadIdx.x;
  const int lane = tid & 63, wave = tid >> 6;
  const int wr = wave >> 1, wc = wave & 1;

  // bijective XCD swizzle: consecutive wgid (same A-panel) -> same XCD chunk
  const int nwg = gridDim.x;
  const int orig = blockIdx.x;
  const int q = nwg >> 3, r = nwg & 7;
  const int xcd = orig & 7;
  const int wgid = (xcd < r ? xcd * (q + 1) : r * (q + 1) + (xcd - r) * q) + (orig >> 3);
  const int bm = (wgid / gx) * 128, bn = (wgid % gx) * 128;

  float4v acc[4][4] = {};

  // staging map: LDS elem off = j*2048 + wave*512 + lane*8
  //   -> row = j*64 + wave*16 + lane/4, col = (lane&3)*8
  const int srow = wave * 16 + (lane >> 2);
  const int scol = (lane & 3) * 8;
  const ushortT* ag0 = A + (size_t)(bm + srow) * K + scol;
  const ushortT* ag1 = A + (size_t)(bm + 64 + srow) * K + scol;
  const ushortT* bg0 = Wt + (size_t)(bn + srow) * K + scol;
  const ushortT* bg1 = Wt + (size_t)(bn + 64 + srow) * K + scol;

  const int fr = lane & 15, g8 = (lane >> 4) * 8;
  const int nt = K >> 5;

  // prologue: stage tiles 0,1,2 (12 loads/wave outstanding)
  #pragma unroll
  for (int t = 0; t < 3; ++t) {
    const int k0 = t << 5;
    gload_lds16(ag0 + k0, &Asl[t][wave * 512]);
    gload_lds16(ag1 + k0, &Asl[t][2048 + wave * 512]);
    gload_lds16(bg0 + k0, &Bsl[t][wave * 512]);
    gload_lds16(bg1 + k0, &Bsl[t][2048 + wave * 512]);
  }

  int bufi = 0;
  for (int t = 0; t < nt; ++t) {
    // tile t ready when outstanding <= 4*(tiles ahead still in flight)
    if (t < nt - 2)      asm volatile("s_waitcnt vmcnt(8)" ::: "memory");
    else if (t == nt - 2) asm volatile("s_waitcnt vmcnt(4)" ::: "memory");
    else                  asm volatile("s_waitcnt vmcnt(0)" ::: "memory");
    __builtin_amdgcn_s_barrier();

    const ushortT* As_ = &Asl[bufi][0];
    const ushortT* Bs_ = &Bsl[bufi][0];
    short8v af[4], bf[4];
    #pragma unroll
    for (int i = 0; i < 4; ++i) {
      af[i] = *(const short8v*)&As_[(wr * 64 + i * 16 + fr) * 32 + g8];
      bf[i] = *(const short8v*)&Bs_[(wc * 64 + i * 16 + fr) * 32 + g8];
    }
    asm volatile("s_waitcnt lgkmcnt(0)" ::: "memory");
    __builtin_amdgcn_sched_barrier(0);  // rule #18: pin MFMA below the wait
    __builtin_amdgcn_s_barrier();       // all waves done reading buf[bufi]

    if (t + 3 < nt) {  // refill this buffer 3 tiles ahead
      const int k0 = (t + 3) << 5;
      gload_lds16(ag0 + k0, &Asl[bufi][wave * 512]);
      gload_lds16(ag1 + k0, &Asl[bufi][2048 + wave * 512]);
      gload_lds16(bg0 + k0, &Bsl[bufi][wave * 512]);
      gload_lds16(bg1 + k0, &Bsl[bufi][2048 + wave * 512]);
    }

    #pragma unroll
    for (int i = 0; i < 4; ++i)
      #pragma unroll
      for (int j = 0; j < 4; ++j)
        acc[i][j] = __builtin_amdgcn_mfma_f32_16x16x32_bf16(af[i], bf[j], acc[i][j], 0, 0, 0);

    bufi = bufi + 1; if (bufi == 3) bufi = 0;
  }

  const int c0 = lane & 15;
  const int r4 = (lane >> 4) * 4;
  #pragma unroll
  for (int i = 0; i < 4; ++i) {
    #pragma unroll
    for (int j = 0; j < 4; ++j) {
      const int col = bn + wc * 64 + j * 16 + c0;
      #pragma unroll
      for (int qq = 0; qq < 4; ++qq) {
        const int row = bm + wr * 64 + i * 16 + r4 + qq;
        if (row < M) {
          float v = acc[i][j][qq] + bias[col];
          if (ACT == 1) v = 0.5f * v * (1.0f + erff(v * 0.70710678118654752f));
          if (RES) v += res[(size_t)row * N + col];
          if (OBF) ((ushortT*)outp)[(size_t)row * N + col] = f2b(v);
          else     ((float*)outp)[(size_t)row * N + col] = v;
        }
      }
    }
  }
}

// ---------------- layernorm f32 -> bf16 (4 rows per 256-thread block) ----------------
__global__ __launch_bounds__(256) void ln_bf16(const float* __restrict__ in, ushortT* __restrict__ out,
                                               const float* __restrict__ g, const float* __restrict__ bb,
                                               int rows) {
  const int r = blockIdx.x * 4 + (threadIdx.x >> 6);
  if (r >= rows) return;
  const int t = threadIdx.x & 63;
  const float* xr = in + (size_t)r * CDIM;
  ushortT* orow = out + (size_t)r * CDIM;
  float v[6];
  float s = 0.f;
  #pragma unroll
  for (int i = 0; i < 6; ++i) { v[i] = xr[i * 64 + t]; s += v[i]; }
  s = wave_sum(s);
  float mean = s * (1.0f / CDIM);
  float q = 0.f;
  #pragma unroll
  for (int i = 0; i < 6; ++i) { float d = v[i] - mean; q += d * d; }
  q = wave_sum(q);
  float rstd = rsqrtf(q * (1.0f / CDIM) + 1e-6f);
  #pragma unroll
  for (int i = 0; i < 6; ++i) {
    int c = i * 64 + t;
    orow[c] = f2b((v[i] - mean) * rstd * g[c] + bb[c]);
  }
}

// ---------------- layernorm f32->f32 ----------------
__global__ __launch_bounds__(64) void ln_kernel(const float* __restrict__ in, float* __restrict__ out,
                                                const float* __restrict__ g, const float* __restrict__ bb,
                                                int rows, size_t in_stride, size_t out_stride) {
  int r = blockIdx.x;
  if (r >= rows) return;
  const float* xr = in + (size_t)r * in_stride;
  float* orow = out + (size_t)r * out_stride;
  int t = threadIdx.x;
  float v[6];
  float s = 0.f;
  #pragma unroll
  for (int i = 0; i < 6; ++i) { v[i] = xr[i * 64 + t]; s += v[i]; }
  s = wave_sum(s);
  float mean = s * (1.0f / CDIM);
  float q = 0.f;
  #pragma unroll
  for (int i = 0; i < 6; ++i) { float d = v[i] - mean; q += d * d; }
  q = wave_sum(q);
  float rstd = rsqrtf(q * (1.0f / CDIM) + 1e-6f);
  #pragma unroll
  for (int i = 0; i < 6; ++i) {
    int c = i * 64 + t;
    orow[c] = (v[i] - mean) * rstd * g[c] + bb[c];
  }
}

// ---------------- attention v3: MFMA ----------------
template<int KS>
__global__ __launch_bounds__(256) void attn3(const ushortT* __restrict__ qkv, ushortT* __restrict__ attnout,
                                             float* __restrict__ cls_attn, int N) {
  constexpr int NT = 2 * KS;
  constexpr int KT = 32 * KS;
  const int h = blockIdx.y, b = blockIdx.z;
  const int rb = blockIdx.x * 64;
  const int tid = threadIdx.x;
  const int w = tid >> 6, l = tid & 63;
  const int c = l & 15, g = l >> 4;

  __shared__ __align__(16) ushortT Vt[64][232];      // V^T: [dim][token]
  __shared__ __align__(16) ushortT Ps[4][16][232];   // per-wave P (bf16)

  const ushortT* bq = qkv + (size_t)(b * N) * 1152 + (size_t)h * 64;

  // ---- stage V transposed ----
  {
    const int vr = tid >> 3, vc = (tid & 7) * 8;
    for (int p = 0; p < KT; p += 32) {
      const int m = vr + p;
      if (m < N) {
        short8v v8 = *(const short8v*)(bq + (size_t)m * 1152 + 768 + vc);
        #pragma unroll
        for (int j = 0; j < 8; ++j) Vt[vc + j][m] = (ushortT)v8[j];
      } else if (m < KT) {
        #pragma unroll
        for (int j = 0; j < 8; ++j) Vt[vc + j][m] = 0;
      }
    }
  }
  __syncthreads();

  // ---- Q A-fragments from global ----
  short8v qf0, qf1;
  {
    int row = rb + 16 * w + c; if (row >= N) row = N - 1;
    const ushortT* qrow = bq + (size_t)row * 1152;
    qf0 = *(const short8v*)(qrow + g * 8);
    qf1 = *(const short8v*)(qrow + 32 + g * 8);
  }

  // ---- S = Q@K^T ----
  float4v sc[NT];
  #pragma unroll
  for (int kt = 0; kt < NT; ++kt) {
    int krow = 16 * kt + c; if (krow >= N) krow = N - 1;
    const ushortT* kr = bq + (size_t)krow * 1152 + 384;
    short8v b0 = *(const short8v*)(kr + g * 8);
    short8v b1 = *(const short8v*)(kr + 32 + g * 8);
    float4v a = {};
    a = __builtin_amdgcn_mfma_f32_16x16x32_bf16(qf0, b0, a, 0, 0, 0);
    a = __builtin_amdgcn_mfma_f32_16x16x32_bf16(qf1, b1, a, 0, 0, 0);
    sc[kt] = a;
  }

  // ---- softmax ----
  float m4[4] = {-INFINITY, -INFINITY, -INFINITY, -INFINITY};
  #pragma unroll
  for (int kt = 0; kt < NT; ++kt) {
    const bool valid = (16 * kt + c) < N;
    #pragma unroll
    for (int q = 0; q < 4; ++q) {
      float s = valid ? sc[kt][q] * 0.125f : -INFINITY;
      sc[kt][q] = s;
      m4[q] = fmaxf(m4[q], s);
    }
  }
  #pragma unroll
  for (int q = 0; q < 4; ++q) {
    #pragma unroll
    for (int o = 1; o <= 8; o <<= 1) m4[q] = fmaxf(m4[q], __shfl_xor(m4[q], o));
  }
  float sum4[4] = {0.f, 0.f, 0.f, 0.f};
  #pragma unroll
  for (int kt = 0; kt < NT; ++kt) {
    #pragma unroll
    for (int q = 0; q < 4; ++q) {
      float e = __expf(sc[kt][q] - m4[q]);
      sc[kt][q] = e;
      sum4[q] += e;
    }
  }
  #pragma unroll
  for (int q = 0; q < 4; ++q) {
    #pragma unroll
    for (int o = 1; o <= 8; o <<= 1) sum4[q] += __shfl_xor(sum4[q], o);
  }
  float inv4[4];
  #pragma unroll
  for (int q = 0; q < 4; ++q) inv4[q] = 1.0f / sum4[q];

  // ---- write P ----
  #pragma unroll
  for (int kt = 0; kt < NT; ++kt) {
    #pragma unroll
    for (int q = 0; q < 4; ++q) Ps[w][4 * g + q][16 * kt + c] = f2b(sc[kt][q]);
  }

  // ---- CLS attention probs ----
  if (rb == 0 && w == 0 && g == 0) {
    const float inv0 = inv4[0];
    #pragma unroll
    for (int kt = 0; kt < NT; ++kt) {
      const int col = 16 * kt + c;
      if (col >= 1 && col < N)
        cls_attn[((size_t)b * NHEADS + h) * (N - 1) + (col - 1)] = sc[kt][0] * inv0;
    }
  }

  // ---- O = P @ V ----
  float4v oacc[4] = {};
  #pragma unroll
  for (int s2 = 0; s2 < KS; ++s2) {
    short8v pa = *(const short8v*)&Ps[w][c][32 * s2 + 8 * g];
    #pragma unroll
    for (int nt = 0; nt < 4; ++nt) {
      short8v vb = *(const short8v*)&Vt[16 * nt + c][32 * s2 + 8 * g];
      oacc[nt] = __builtin_amdgcn_mfma_f32_16x16x32_bf16(pa, vb, oacc[nt], 0, 0, 0);
    }
  }

  // ---- epilogue ----
  #pragma unroll
  for (int nt = 0; nt < 4; ++nt) {
    #pragma unroll
    for (int q = 0; q < 4; ++q) {
      const int row = rb + 16 * w + 4 * g + q;
      if (row < N)
        attnout[((size_t)(b * N + row)) * CDIM + h * 64 + 16 * nt + c] = f2b(oacc[nt][q] * inv4[q]);
    }
  }
}

// ---------------- fused clsscore + rank top-k ----------------
__global__ __launch_bounds__(256) void topk_rank(const float* __restrict__ cls_attn, int* __restrict__ idx,
                                                 int Nm1, int Kkeep) {
  const int b = blockIdx.x;
  const int t = threadIdx.x;
  __shared__ float s_sc[224];
  if (t < Nm1) {
    const float* ca = cls_attn + (size_t)b * NHEADS * Nm1 + t;
    float s = 0.f;
    #pragma unroll
    for (int h = 0; h < NHEADS; ++h) s += ca[h * Nm1];
    s_sc[t] = s * (1.0f / NHEADS);
  }
  __syncthreads();
  if (t < Nm1) {
    const float mys = s_sc[t];
    int r = 0;
    for (int i = 0; i < Nm1; ++i) {
      float si = s_sc[i];
      r += (si > mys || (si == mys && i < t)) ? 1 : 0;
    }
    if (r < Kkeep) idx[b * Kkeep + r] = t;
  }
}

// ---------------- gather pruned tokens ----------------
__global__ __launch_bounds__(256) void gather_kernel(const float* __restrict__ h, const int* __restrict__ idx,
                                                     float* __restrict__ outb, int N, int Kkeep) {
  size_t total = (size_t)BATCH * (1 + Kkeep) * CDIM;
  size_t i = (size_t)blockIdx.x * 256 + threadIdx.x;
  if (i >= total) return;
  int c = (int)(i % CDIM);
  size_t r = i / CDIM;
  int n = (int)(r % (1 + Kkeep));
  int b = (int)(r / (1 + Kkeep));
  int src = (n == 0) ? 0 : 1 + idx[b * Kkeep + (n - 1)];
  outb[i] = h[((size_t)b * N + src) * CDIM + c];
}

// ---------------- small f32 GEMM (head only) ----------------
__global__ __launch_bounds__(256) void gemm_f32(const float* __restrict__ A, const float* __restrict__ W,
                                                const float* __restrict__ bias, float* __restrict__ out,
                                                int M, int N, int K) {
  __shared__ __align__(16) float As[16][64];
  __shared__ __align__(16) float Ws[16][64];
  const int tid = threadIdx.x;
  const int tx = tid & 15, ty = tid >> 4;
  const int bm = blockIdx.y * 64, bn = blockIdx.x * 64;
  float acc[4][4] = {};
  const int ma = tid >> 2;
  const int ka = (tid & 3) << 2;
  const int kw = ty;
  const int nw = tx << 2;
  for (int k0 = 0; k0 < K; k0 += 16) {
    {
      float4 a4 = make_float4(0.f, 0.f, 0.f, 0.f);
      if (bm + ma < M) a4 = *reinterpret_cast<const float4*>(&A[(size_t)(bm + ma) * K + k0 + ka]);
      As[ka + 0][ma] = a4.x; As[ka + 1][ma] = a4.y; As[ka + 2][ma] = a4.z; As[ka + 3][ma] = a4.w;
    }
    {
      const int gn = bn + nw;
      const float* wp = &W[(size_t)(k0 + kw) * N + gn];
      #pragma unroll
      for (int j = 0; j < 4; ++j) Ws[kw][nw + j] = (gn + j < N) ? wp[j] : 0.f;
    }
    __syncthreads();
    #pragma unroll
    for (int kk = 0; kk < 16; ++kk) {
      float4 a = *reinterpret_cast<const float4*>(&As[kk][ty << 2]);
      float4 w = *reinterpret_cast<const float4*>(&Ws[kk][tx << 2]);
      float av[4] = {a.x, a.y, a.z, a.w};
      float wv[4] = {w.x, w.y, w.z, w.w};
      #pragma unroll
      for (int i = 0; i < 4; ++i)
        #pragma unroll
        for (int j = 0; j < 4; ++j)
          acc[i][j] = fmaf(av[i], wv[j], acc[i][j]);
    }
    __syncthreads();
  }
  #pragma unroll
  for (int i = 0; i < 4; ++i) {
    int r = bm + (ty << 2) + i;
    if (r >= M) continue;
    #pragma unroll
    for (int j = 0; j < 4; ++j) {
      int cidx = bn + (tx << 2) + j;
      if (cidx >= N) continue;
      out[(size_t)r * N + cidx] = acc[i][j] + bias[cidx];
    }
  }
}

// ---------------- host launch ----------------
extern "C" void kernel_launch(void* const* d_in, const int* in_sizes, int n_in,
                              void* d_out, int out_size, void* d_ws, size_t ws_size,
                              hipStream_t stream) {
  const float* x        = (const float*)d_in[0];
  const float* patch_w  = (const float*)d_in[1];
  const float* patch_b  = (const float*)d_in[2];
  const float* cls_tok  = (const float*)d_in[3];
  const float* pos      = (const float*)d_in[4];
  const float* ln1_g    = (const float*)d_in[5];
  const float* ln1_b    = (const float*)d_in[6];
  const float* qkv_w    = (const float*)d_in[7];
  const float* qkv_b    = (const float*)d_in[8];
  const float* proj_w   = (const float*)d_in[9];
  const float* proj_b   = (const float*)d_in[10];
  const float* ln2_g    = (const float*)d_in[11];
  const float* ln2_b    = (const float*)d_in[12];
  const float* fc1_w    = (const float*)d_in[13];
  const float* fc1_b    = (const float*)d_in[14];
  const float* fc2_w    = (const float*)d_in[15];
  const float* fc2_b    = (const float*)d_in[16];
  const float* norm_g   = (const float*)d_in[17];
  const float* norm_b   = (const float*)d_in[18];
  const float* head_w   = (const float*)d_in[19];
  const float* head_b   = (const float*)d_in[20];
  float* out = (float*)d_out;

  float* ws = (float*)d_ws;
  // ---- workspace layout (float offsets) ----
  float* hA       = ws;                          // [B,197,C] f32
  float* big      = ws + 4841472;                // qkv bf16 / fc1 hidden bf16 / im2col / patchout
  ushortT* big_u  = (ushortT*)big;
  float* patchout = big + 4816896;               // f32, patch-embed only
  float* hB       = ws + 14524416;               // [B,<=197,C] f32 ping-pong
  ushortT* lnb_u  = (ushortT*)(ws + 19365888);
  ushortT* attn_u = (ushortT*)(ws + 21786624);
  ushortT* wbuf_u = (ushortT*)(ws + 24207360);
  float* cls_attn = ws + 25092096;
  int*   idxbuf   = (int*)(ws + 25179904);
  float* cls0     = ws + 25191168;

  ushortT* wq = wbuf_u;
  ushortT* wp = wbuf_u + 442368;
  ushortT* w1 = wbuf_u + 589824;
  ushortT* w2 = wbuf_u + 1179648;

  // ---- patch embed ----
  {
    int total = BATCH * NPATCH * 768;
    im2col_bf16<<<(total + 255) / 256, 256, 0, stream>>>(x, big_u);
    wtrans_one<<<288, 256, 0, stream>>>(patch_w, wbuf_u, 768, CDIM);
    gemm_mfma<0, 0, 0><<<3 * 98, 256, 0, stream>>>(big_u, wbuf_u, patch_b, nullptr, patchout,
                                                   BATCH * NPATCH, CDIM, 768, 3);
    int tot2 = BATCH * NTOK0 * CDIM;
    assemble_kernel<<<(tot2 + 255) / 256, 256, 0, stream>>>(patchout, cls_tok, pos, hA);
  }

  float* h = hA;
  float* hOther = hB;
  int ncur = NTOK0;
  for (int i = 0; i < NLAYERS; ++i) {
    int M = BATCH * ncur;
    int gy = (M + 127) / 128;
    wtrans_layer<<<1728, 256, 0, stream>>>(qkv_w + (size_t)i * CDIM * 3 * CDIM,
                                           proj_w + (size_t)i * CDIM * CDIM,
                                           fc1_w + (size_t)i * CDIM * MLPD,
                                           fc2_w + (size_t)i * MLPD * CDIM,
                                           wq, wp, w1, w2);
    ln_bf16<<<(M + 3) / 4, 256, 0, stream>>>(h, lnb_u, ln1_g + i * CDIM, ln1_b + i * CDIM, M);
    gemm_mfma<0, 0, 1><<<9 * gy, 256, 0, stream>>>(lnb_u, wq, qkv_b + i * 3 * CDIM, nullptr,
                                                   big_u, M, 3 * CDIM, CDIM, 9);
    // attention (MFMA)
    {
      dim3 g((ncur + 63) / 64, NHEADS, BATCH);
      int ks = (ncur + 31) / 32;
      if (ks == 7)      attn3<7><<<g, 256, 0, stream>>>(big_u, attn_u, cls_attn, ncur);
      else if (ks == 6) attn3<6><<<g, 256, 0, stream>>>(big_u, attn_u, cls_attn, ncur);
      else if (ks == 5) attn3<5><<<g, 256, 0, stream>>>(big_u, attn_u, cls_attn, ncur);
      else              attn3<4><<<g, 256, 0, stream>>>(big_u, attn_u, cls_attn, ncur);
    }
    gemm_mfma<0, 1, 0><<<3 * gy, 256, 0, stream>>>(attn_u, wp, proj_b + i * CDIM, h,
                                                   h, M, CDIM, CDIM, 3);
    if (i == 2 || i == 4 || i == 6) {
      int keep = (i == 2) ? 176 : (i == 4) ? 149 : 119;
      int Nm1 = ncur - 1;
      topk_rank<<<BATCH, 256, 0, stream>>>(cls_attn, idxbuf, Nm1, keep);
      int newN = 1 + keep;
      size_t gtot = (size_t)BATCH * newN * CDIM;
      gather_kernel<<<(int)((gtot + 255) / 256), 256, 0, stream>>>(h, idxbuf, hOther, ncur, keep);
      float* tmp = h; h = hOther; hOther = tmp;
      ncur = newN;
      M = BATCH * ncur;
      gy = (M + 127) / 128;
    }
    ln_bf16<<<(M + 3) / 4, 256, 0, stream>>>(h, lnb_u, ln2_g + i * CDIM, ln2_b + i * CDIM, M);
    gemm_mfma<1, 0, 1><<<12 * gy, 256, 0, stream>>>(lnb_u, w1, fc1_b + i * MLPD, nullptr,
                                                    big_u, M, MLPD, CDIM, 12);
    gemm_mfma<0, 1, 0><<<3 * gy, 256, 0, stream>>>(big_u, w2, fc2_b + i * CDIM, h,
                                                   h, M, CDIM, MLPD, 3);
  }

  ln_kernel<<<BATCH, 64, 0, stream>>>(h, cls0, norm_g, norm_b, BATCH, (size_t)ncur * CDIM, CDIM);
  gemm_f32<<<dim3(2, 1), 256, 0, stream>>>(cls0, head_w, head_b, out, BATCH, NCLS, CDIM);
}